// Round 4
// baseline (390.825 us; speedup 1.0000x reference)
//
#include <hip/hip_runtime.h>
#include <stdint.h>

// GatedLSTM — single persistent kernel (+ nothing else).
// Blocks 0..63: char LSTM chain (13 pipelined steps, 64-block agent-scope barrier),
//   mix (char outputs + cte@c2 + scalar gate), word LSTM layer0/1, then set flag.
// Blocks 64..255: prefetch dec_W (100 MB) into LLC while the chain runs, then wait on flag.
// All 256 blocks: decoder matvec y = dec_W @ hw2 + dec_b (wave-per-row).
// fp32 I/O throughout (reference dtypes are float32).

#define NCHAR 64
#define NBLK  256
#define BAR_I 3072      // int index into ws where barrier slots live (bytes 12288..12415)
#define FLAG_SLOT 20

static __device__ __forceinline__ float dot4(float4 w, const float* p){
    return w.x*p[0] + w.y*p[1] + w.z*p[2] + w.w*p[3];
}
static __device__ __forceinline__ float sigf(float x){ return 1.0f / (1.0f + __expf(-x)); }
static __device__ __forceinline__ float tanhf_(float x){
    x = fminf(fmaxf(x, -15.0f), 15.0f);
    float e = __expf(2.0f * x);
    return (e - 1.0f) / (e + 1.0f);
}

// 64-block barrier: release-add arrival; relaxed spin; single acquire on exit.
static __device__ __forceinline__ void gbar(int* bar, int slot, int n){
    __syncthreads();
    if (threadIdx.x == 0){
        __hip_atomic_fetch_add(bar + slot, 1, __ATOMIC_RELEASE, __HIP_MEMORY_SCOPE_AGENT);
        while (__hip_atomic_load(bar + slot, __ATOMIC_RELAXED, __HIP_MEMORY_SCOPE_AGENT) < n)
            __builtin_amdgcn_s_sleep(1);
        (void)__hip_atomic_load(bar + slot, __ATOMIC_ACQUIRE, __HIP_MEMORY_SCOPE_AGENT);
    }
    __syncthreads();
}

// ws layout (floats):
//   0    : h1 double buffer [2][256]   (char layer0 hidden)
//   512  : h2 double buffer [2][256]   (char layer1 hidden)
//   1024 : c1 [256], 1280: c2 [256]    (block-exclusive)
//   1536 : xcw [512]  (cte @ c2)
//   2048 : hw1 [512], 2560: hw2 [512]
//   3072(int) : barrier slots [32]
//   8192 : prefetch anti-DCE dump [49152]

__global__ __launch_bounds__(256) void k_fused(
    const int* x_word, const int* x_char,
    const float* hwh, const float* hwc, const float* hch, const float* hcc,
    const float* word_emb, const float* wWih, const float* wWhh,
    const float* wbih, const float* wbhh,
    const float* dec_W, const float* dec_b,
    const float* char_emb, const float* cWih, const float* cWhh,
    const float* cbih, const float* cbhh,
    const float* cte, const float* g_w, const float* g_b,
    float* ws, int* bar, float* out)
{
    const int tid = threadIdx.x;
    const int bx = blockIdx.x;

    __shared__ float sH1[256], sH2[256], sE[256];
    __shared__ float sg1[16], sg2[16];
    __shared__ float sX[512];
    __shared__ float sgw[32];
    __shared__ float sw4[4];
    __shared__ float s_g;

    if (bx < NCHAR){
        float* h1b = ws;
        float* h2b = ws + 512;
        float* c1  = ws + 1024;
        float* c2  = ws + 1280;

        const int rg = tid >> 4;        // 0..15
        const int lane16 = tid & 15;
        const int gate = rg & 3;
        const int uu = rg >> 2;         // 0..3
        const int u = (bx << 2) + uu;   // 0..255
        const int row = (gate << 8) + u;

        // ---- char chain: pipelined (layer1@t + layer2@t-1) ----
        for (int t = 0; t <= 12; ++t){
            sH1[tid] = (t == 0) ? hch[tid] : h1b[(t & 1)*256 + tid];
            if (t >= 1) sH2[tid] = (t == 1) ? hch[256 + tid] : h2b[((t-1) & 1)*256 + tid];
            if (t < 12) sE[tid] = char_emb[x_char[t]*256 + tid];
            __syncthreads();

            float a1 = 0.f, a2 = 0.f;
            if (t < 12){
                const float4* wi = (const float4*)(cWih + (size_t)row*256) + lane16*4;
                const float4* wh = (const float4*)(cWhh + (size_t)row*256) + lane16*4;
                const float* xp = sE  + lane16*16;
                const float* hp = sH1 + lane16*16;
                #pragma unroll
                for (int j = 0; j < 4; ++j) a1 += dot4(wi[j], xp + 4*j) + dot4(wh[j], hp + 4*j);
            }
            if (t >= 1){
                const size_t r2 = (size_t)(1024 + row);
                const float4* wi = (const float4*)(cWih + r2*256) + lane16*4;
                const float4* wh = (const float4*)(cWhh + r2*256) + lane16*4;
                const float* xp = sH1 + lane16*16;
                const float* hp = sH2 + lane16*16;
                #pragma unroll
                for (int j = 0; j < 4; ++j) a2 += dot4(wi[j], xp + 4*j) + dot4(wh[j], hp + 4*j);
            }
            #pragma unroll
            for (int m = 8; m >= 1; m >>= 1){
                a1 += __shfl_xor(a1, m, 64);
                a2 += __shfl_xor(a2, m, 64);
            }
            if (lane16 == 0){
                if (t < 12) sg1[rg] = a1 + cbih[row]        + cbhh[row];
                if (t >= 1) sg2[rg] = a2 + cbih[1024 + row] + cbhh[1024 + row];
            }
            __syncthreads();

            if (tid < 4){
                if (t < 12){
                    int uh = (bx << 2) + tid;
                    float gi = sigf(sg1[tid*4+0]);
                    float gf = sigf(sg1[tid*4+1]);
                    float gg = tanhf_(sg1[tid*4+2]);
                    float go = sigf(sg1[tid*4+3]);
                    float cp = (t == 0) ? hcc[uh] : c1[uh];
                    float c = gf * cp + gi * gg;
                    c1[uh] = c;
                    h1b[((t+1) & 1)*256 + uh] = go * tanhf_(c);
                }
            } else if (tid < 8){
                if (t >= 1){
                    int q = tid - 4;
                    int uh = (bx << 2) + q;
                    float gi = sigf(sg2[q*4+0]);
                    float gf = sigf(sg2[q*4+1]);
                    float gg = tanhf_(sg2[q*4+2]);
                    float go = sigf(sg2[q*4+3]);
                    float cp = (t == 1) ? hcc[256 + uh] : c2[uh];
                    float c = gf * cp + gi * gg;
                    c2[uh] = c;
                    h2b[(t & 1)*256 + uh] = go * tanhf_(c);
                }
            }
            gbar(bar, t, NCHAR);
        }

        // ---- mix: char outputs, scalar gate, xcw = cte @ c2 ----
        sH1[tid] = c2[tid];
        if (tid < 4){
            int uh = (bx << 2) + tid;
            out[52048 + uh]       = h1b[uh];        // final h1 in buffer 0
            out[52048 + 256 + uh] = h2b[uh];        // final h2 in buffer 0
            out[52560 + uh]       = c1[uh];
            out[52560 + 256 + uh] = c2[uh];
        }
        const size_t wbase = (size_t)x_word[0] * 512;
        {
            float p = g_w[2*tid]   * word_emb[wbase + 2*tid]
                    + g_w[2*tid+1] * word_emb[wbase + 2*tid+1];
            #pragma unroll
            for (int m = 32; m >= 1; m >>= 1) p += __shfl_xor(p, m, 64);
            if ((tid & 63) == 0) sw4[tid >> 6] = p;
        }
        __syncthreads();   // covers sH1 writes + sw4
        if (tid == 0) s_g = fmaxf(sw4[0] + sw4[1] + sw4[2] + sw4[3] + g_b[0], 0.0f);
        {
            const int rr = tid >> 5;
            const int lane32 = tid & 31;
            const int crow = (bx << 3) + rr;   // 0..511
            const float4* wp = (const float4*)(cte + (size_t)crow*256) + lane32*2;
            float acc = dot4(wp[0], sH1 + lane32*8) + dot4(wp[1], sH1 + lane32*8 + 4);
            #pragma unroll
            for (int m = 16; m >= 1; m >>= 1) acc += __shfl_xor(acc, m, 64);
            if (lane32 == 0) ws[1536 + crow] = acc;
        }
        gbar(bar, 13, NCHAR);

        // ---- word layer 0 ----
        const int rg8 = tid >> 3;       // 0..31
        const int lane8 = tid & 7;
        const int wgate = rg8 & 3;
        const int wuu = rg8 >> 2;       // 0..7
        const int uw = (bx << 3) + wuu; // 0..511
        const int wrow = (wgate << 9) + uw;
        {
            float g = s_g;
            sX[2*tid]   = (1.0f - g) * word_emb[wbase + 2*tid]   + g * ws[1536 + 2*tid];
            sX[2*tid+1] = (1.0f - g) * word_emb[wbase + 2*tid+1] + g * ws[1536 + 2*tid+1];
        }
        __syncthreads();
        {
            const size_t rf = (size_t)wrow;
            const float4* wi = (const float4*)(wWih + rf*512) + lane8*16;
            const float4* wh = (const float4*)(wWhh + rf*512) + lane8*16;
            const float4* hv = (const float4*)(hwh) + lane8*16;
            const float* xp = sX + lane8*64;
            float acc = 0.f;
            #pragma unroll
            for (int j = 0; j < 16; ++j){
                float4 h4 = hv[j];
                acc += dot4(wi[j], xp + 4*j);
                float4 w4 = wh[j];
                acc += w4.x*h4.x + w4.y*h4.y + w4.z*h4.z + w4.w*h4.w;
            }
            #pragma unroll
            for (int m = 4; m >= 1; m >>= 1) acc += __shfl_xor(acc, m, 64);
            if (lane8 == 0) sgw[rg8] = acc + wbih[rf] + wbhh[rf];
        }
        __syncthreads();
        if (tid < 8){
            int u2 = (bx << 3) + tid;
            float gi = sigf(sgw[tid*4+0]);
            float gf = sigf(sgw[tid*4+1]);
            float gg = tanhf_(sgw[tid*4+2]);
            float go = sigf(sgw[tid*4+3]);
            float c = gf * hwc[u2] + gi * gg;
            float h = go * tanhf_(c);
            ws[2048 + u2] = h;
            out[50000 + u2] = h;
            out[51024 + u2] = c;
        }
        gbar(bar, 14, NCHAR);

        // ---- word layer 1 ----
        sX[2*tid]   = ws[2048 + 2*tid];
        sX[2*tid+1] = ws[2048 + 2*tid+1];
        __syncthreads();
        {
            const size_t rf = (size_t)(2048 + wrow);
            const float4* wi = (const float4*)(wWih + rf*512) + lane8*16;
            const float4* wh = (const float4*)(wWhh + rf*512) + lane8*16;
            const float4* hv = (const float4*)(hwh + 512) + lane8*16;
            const float* xp = sX + lane8*64;
            float acc = 0.f;
            #pragma unroll
            for (int j = 0; j < 16; ++j){
                float4 h4 = hv[j];
                acc += dot4(wi[j], xp + 4*j);
                float4 w4 = wh[j];
                acc += w4.x*h4.x + w4.y*h4.y + w4.z*h4.z + w4.w*h4.w;
            }
            #pragma unroll
            for (int m = 4; m >= 1; m >>= 1) acc += __shfl_xor(acc, m, 64);
            if (lane8 == 0) sgw[rg8] = acc + wbih[rf] + wbhh[rf];
        }
        __syncthreads();
        if (tid < 8){
            int u2 = (bx << 3) + tid;
            float gi = sigf(sgw[tid*4+0]);
            float gf = sigf(sgw[tid*4+1]);
            float gg = tanhf_(sgw[tid*4+2]);
            float go = sigf(sgw[tid*4+3]);
            float c = gf * hwc[512 + u2] + gi * gg;
            float h = go * tanhf_(c);
            ws[2560 + u2] = h;
            out[50000 + 512 + u2] = h;
            out[51024 + 512 + u2] = c;
        }
        gbar(bar, 15, NCHAR);
        if (bx == 0 && tid == 0)
            __hip_atomic_store(bar + FLAG_SLOT, 1, __ATOMIC_RELEASE, __HIP_MEMORY_SCOPE_AGENT);
    } else {
        // ---- prefetch dec_W into LLC while the chain runs ----
        const float4* dw = (const float4*)dec_W;
        const int gid = (bx - NCHAR)*256 + tid;     // 0..49151
        float acc = 0.f;
        for (int i = gid; i < 6400000; i += 49152){
            float4 v = dw[i];
            acc += v.x + v.y + v.z + v.w;
        }
        ws[8192 + gid] = acc;   // anti-DCE dump (region unused otherwise)
        __syncthreads();
        if (tid == 0){
            while (__hip_atomic_load(bar + FLAG_SLOT, __ATOMIC_RELAXED, __HIP_MEMORY_SCOPE_AGENT) == 0)
                __builtin_amdgcn_s_sleep(4);
            (void)__hip_atomic_load(bar + FLAG_SLOT, __ATOMIC_ACQUIRE, __HIP_MEMORY_SCOPE_AGENT);
        }
        __syncthreads();
    }

    // ---- decoder: all 256 blocks, wave-per-row ----
    const int lane = tid & 63;
    const int wid = (bx << 2) + (tid >> 6);   // 0..1023
    const float4* hp = (const float4*)(ws + 2560) + lane*2;
    float4 ha = hp[0], hb = hp[1];
    float hx0[4] = {ha.x, ha.y, ha.z, ha.w};
    float hx1[4] = {hb.x, hb.y, hb.z, hb.w};
    for (int r = wid; r < 50000; r += 1024){
        const float4* wp = (const float4*)(dec_W + (size_t)r*512) + lane*2;
        float acc = dot4(wp[0], hx0) + dot4(wp[1], hx1);
        #pragma unroll
        for (int m = 32; m >= 1; m >>= 1) acc += __shfl_xor(acc, m, 64);
        if (lane == 0) out[r] = acc + dec_b[r];
    }
}

extern "C" void kernel_launch(void* const* d_in, const int* in_sizes, int n_in,
                              void* d_out, int out_size, void* d_ws, size_t ws_size,
                              hipStream_t stream)
{
    const int*   x_word   = (const int*)d_in[0];
    const int*   x_char   = (const int*)d_in[1];
    const float* hwh      = (const float*)d_in[2];
    const float* hwc      = (const float*)d_in[3];
    const float* hch      = (const float*)d_in[4];
    const float* hcc      = (const float*)d_in[5];
    const float* word_emb = (const float*)d_in[6];
    const float* wWih     = (const float*)d_in[7];
    const float* wWhh     = (const float*)d_in[8];
    const float* wbih     = (const float*)d_in[9];
    const float* wbhh     = (const float*)d_in[10];
    const float* dec_W    = (const float*)d_in[11];
    const float* dec_b    = (const float*)d_in[12];
    const float* char_emb = (const float*)d_in[13];
    const float* cWih     = (const float*)d_in[14];
    const float* cWhh     = (const float*)d_in[15];
    const float* cbih     = (const float*)d_in[16];
    const float* cbhh     = (const float*)d_in[17];
    const float* cte      = (const float*)d_in[18];
    const float* g_w      = (const float*)d_in[19];
    const float* g_b      = (const float*)d_in[20];

    float* ws = (float*)d_ws;
    int* bar = (int*)((char*)d_ws + BAR_I*4);
    hipMemsetAsync(bar, 0, 32 * sizeof(int), stream);

    hipLaunchKernelGGL(k_fused, dim3(NBLK), dim3(256), 0, stream,
        x_word, x_char, hwh, hwc, hch, hcc, word_emb, wWih, wWhh, wbih, wbhh,
        dec_W, dec_b, char_emb, cWih, cWhh, cbih, cbhh, cte, g_w, g_b,
        ws, bar, (float*)d_out);
}

// Round 5
// 372.431 us; speedup vs baseline: 1.0494x; 1.0494x over previous
//
#include <hip/hip_runtime.h>
#include <stdint.h>

// GatedLSTM — single persistent kernel.
// Blocks 0..63: char LSTM chain (13 pipelined steps, 64-block agent-scope barrier),
//   mix (char outputs + cte@c2 + scalar gate), word LSTM layer0/1, then set flag.
// Blocks 64..255: prefetch dec_W (100 MB) into LLC with 8-deep MLP while chain runs,
//   then wait on flag. All 256 blocks: decoder matvec, 4 rows/wave/iter (8 loads in flight).
// fp32 I/O throughout.

#define NCHAR 64
#define NBLK  256
#define BAR_I 3072      // int index into ws where barrier slots live
#define FLAG_SLOT 20

static __device__ __forceinline__ float dot4(float4 w, const float* p){
    return w.x*p[0] + w.y*p[1] + w.z*p[2] + w.w*p[3];
}
static __device__ __forceinline__ float sigf(float x){ return 1.0f / (1.0f + __expf(-x)); }
static __device__ __forceinline__ float tanhf_(float x){
    x = fminf(fmaxf(x, -15.0f), 15.0f);
    float e = __expf(2.0f * x);
    return (e - 1.0f) / (e + 1.0f);
}

// 64-block barrier: release-add arrival; relaxed spin; single acquire on exit.
static __device__ __forceinline__ void gbar(int* bar, int slot, int n){
    __syncthreads();
    if (threadIdx.x == 0){
        __hip_atomic_fetch_add(bar + slot, 1, __ATOMIC_RELEASE, __HIP_MEMORY_SCOPE_AGENT);
        while (__hip_atomic_load(bar + slot, __ATOMIC_RELAXED, __HIP_MEMORY_SCOPE_AGENT) < n)
            __builtin_amdgcn_s_sleep(1);
        (void)__hip_atomic_load(bar + slot, __ATOMIC_ACQUIRE, __HIP_MEMORY_SCOPE_AGENT);
    }
    __syncthreads();
}

// ws layout (floats):
//   0: h1 dbuf [2][256] | 512: h2 dbuf [2][256] | 1024: c1[256] | 1280: c2[256]
//   1536: xcw[512] | 2048: hw1[512] | 2560: hw2[512]
//   3072(int): barrier slots[32] | 8192: prefetch anti-DCE dump[49152]

__global__ __launch_bounds__(256) void k_fused(
    const int* x_word, const int* x_char,
    const float* hwh, const float* hwc, const float* hch, const float* hcc,
    const float* word_emb, const float* wWih, const float* wWhh,
    const float* wbih, const float* wbhh,
    const float* dec_W, const float* dec_b,
    const float* char_emb, const float* cWih, const float* cWhh,
    const float* cbih, const float* cbhh,
    const float* cte, const float* g_w, const float* g_b,
    float* ws, int* bar, float* out)
{
    const int tid = threadIdx.x;
    const int bx = blockIdx.x;

    __shared__ float sH1[256], sH2[256], sE[256];
    __shared__ float sg1[16], sg2[16];
    __shared__ float sX[512];
    __shared__ float sgw[32];
    __shared__ float sw4[4];
    __shared__ float s_g;

    if (bx < NCHAR){
        float* h1b = ws;
        float* h2b = ws + 512;
        float* c1  = ws + 1024;
        float* c2  = ws + 1280;

        const int rg = tid >> 4;        // 0..15
        const int lane16 = tid & 15;
        const int gate = rg & 3;
        const int uu = rg >> 2;         // 0..3
        const int u = (bx << 2) + uu;   // 0..255
        const int row = (gate << 8) + u;

        // ---- char chain: pipelined (layer1@t + layer2@t-1) ----
        for (int t = 0; t <= 12; ++t){
            sH1[tid] = (t == 0) ? hch[tid] : h1b[(t & 1)*256 + tid];
            if (t >= 1) sH2[tid] = (t == 1) ? hch[256 + tid] : h2b[((t-1) & 1)*256 + tid];
            if (t < 12) sE[tid] = char_emb[x_char[t]*256 + tid];
            __syncthreads();

            float a1 = 0.f, a2 = 0.f;
            if (t < 12){
                const float4* wi = (const float4*)(cWih + (size_t)row*256) + lane16*4;
                const float4* wh = (const float4*)(cWhh + (size_t)row*256) + lane16*4;
                const float* xp = sE  + lane16*16;
                const float* hp = sH1 + lane16*16;
                #pragma unroll
                for (int j = 0; j < 4; ++j) a1 += dot4(wi[j], xp + 4*j) + dot4(wh[j], hp + 4*j);
            }
            if (t >= 1){
                const size_t r2 = (size_t)(1024 + row);
                const float4* wi = (const float4*)(cWih + r2*256) + lane16*4;
                const float4* wh = (const float4*)(cWhh + r2*256) + lane16*4;
                const float* xp = sH1 + lane16*16;
                const float* hp = sH2 + lane16*16;
                #pragma unroll
                for (int j = 0; j < 4; ++j) a2 += dot4(wi[j], xp + 4*j) + dot4(wh[j], hp + 4*j);
            }
            #pragma unroll
            for (int m = 8; m >= 1; m >>= 1){
                a1 += __shfl_xor(a1, m, 64);
                a2 += __shfl_xor(a2, m, 64);
            }
            if (lane16 == 0){
                if (t < 12) sg1[rg] = a1 + cbih[row]        + cbhh[row];
                if (t >= 1) sg2[rg] = a2 + cbih[1024 + row] + cbhh[1024 + row];
            }
            __syncthreads();

            if (tid < 4){
                if (t < 12){
                    int uh = (bx << 2) + tid;
                    float gi = sigf(sg1[tid*4+0]);
                    float gf = sigf(sg1[tid*4+1]);
                    float gg = tanhf_(sg1[tid*4+2]);
                    float go = sigf(sg1[tid*4+3]);
                    float cp = (t == 0) ? hcc[uh] : c1[uh];
                    float c = gf * cp + gi * gg;
                    c1[uh] = c;
                    h1b[((t+1) & 1)*256 + uh] = go * tanhf_(c);
                }
            } else if (tid < 8){
                if (t >= 1){
                    int q = tid - 4;
                    int uh = (bx << 2) + q;
                    float gi = sigf(sg2[q*4+0]);
                    float gf = sigf(sg2[q*4+1]);
                    float gg = tanhf_(sg2[q*4+2]);
                    float go = sigf(sg2[q*4+3]);
                    float cp = (t == 1) ? hcc[256 + uh] : c2[uh];
                    float c = gf * cp + gi * gg;
                    c2[uh] = c;
                    h2b[(t & 1)*256 + uh] = go * tanhf_(c);
                }
            }
            gbar(bar, t, NCHAR);
        }

        // ---- mix: char outputs, scalar gate, xcw = cte @ c2 ----
        sH1[tid] = c2[tid];
        if (tid < 4){
            int uh = (bx << 2) + tid;
            out[52048 + uh]       = h1b[uh];
            out[52048 + 256 + uh] = h2b[uh];
            out[52560 + uh]       = c1[uh];
            out[52560 + 256 + uh] = c2[uh];
        }
        const size_t wbase = (size_t)x_word[0] * 512;
        {
            float p = g_w[2*tid]   * word_emb[wbase + 2*tid]
                    + g_w[2*tid+1] * word_emb[wbase + 2*tid+1];
            #pragma unroll
            for (int m = 32; m >= 1; m >>= 1) p += __shfl_xor(p, m, 64);
            if ((tid & 63) == 0) sw4[tid >> 6] = p;
        }
        __syncthreads();
        if (tid == 0) s_g = fmaxf(sw4[0] + sw4[1] + sw4[2] + sw4[3] + g_b[0], 0.0f);
        {
            const int rr = tid >> 5;
            const int lane32 = tid & 31;
            const int crow = (bx << 3) + rr;
            const float4* wp = (const float4*)(cte + (size_t)crow*256) + lane32*2;
            float acc = dot4(wp[0], sH1 + lane32*8) + dot4(wp[1], sH1 + lane32*8 + 4);
            #pragma unroll
            for (int m = 16; m >= 1; m >>= 1) acc += __shfl_xor(acc, m, 64);
            if (lane32 == 0) ws[1536 + crow] = acc;
        }
        gbar(bar, 13, NCHAR);

        // ---- word layer 0 ----
        const int rg8 = tid >> 3;
        const int lane8 = tid & 7;
        const int wgate = rg8 & 3;
        const int wuu = rg8 >> 2;
        const int uw = (bx << 3) + wuu;
        const int wrow = (wgate << 9) + uw;
        {
            float g = s_g;
            sX[2*tid]   = (1.0f - g) * word_emb[wbase + 2*tid]   + g * ws[1536 + 2*tid];
            sX[2*tid+1] = (1.0f - g) * word_emb[wbase + 2*tid+1] + g * ws[1536 + 2*tid+1];
        }
        __syncthreads();
        {
            const size_t rf = (size_t)wrow;
            const float4* wi = (const float4*)(wWih + rf*512) + lane8*16;
            const float4* wh = (const float4*)(wWhh + rf*512) + lane8*16;
            const float4* hv = (const float4*)(hwh) + lane8*16;
            const float* xp = sX + lane8*64;
            float acc = 0.f;
            #pragma unroll
            for (int j = 0; j < 16; ++j){
                float4 h4 = hv[j];
                acc += dot4(wi[j], xp + 4*j);
                float4 w4 = wh[j];
                acc += w4.x*h4.x + w4.y*h4.y + w4.z*h4.z + w4.w*h4.w;
            }
            #pragma unroll
            for (int m = 4; m >= 1; m >>= 1) acc += __shfl_xor(acc, m, 64);
            if (lane8 == 0) sgw[rg8] = acc + wbih[rf] + wbhh[rf];
        }
        __syncthreads();
        if (tid < 8){
            int u2 = (bx << 3) + tid;
            float gi = sigf(sgw[tid*4+0]);
            float gf = sigf(sgw[tid*4+1]);
            float gg = tanhf_(sgw[tid*4+2]);
            float go = sigf(sgw[tid*4+3]);
            float c = gf * hwc[u2] + gi * gg;
            float h = go * tanhf_(c);
            ws[2048 + u2] = h;
            out[50000 + u2] = h;
            out[51024 + u2] = c;
        }
        gbar(bar, 14, NCHAR);

        // ---- word layer 1 ----
        sX[2*tid]   = ws[2048 + 2*tid];
        sX[2*tid+1] = ws[2048 + 2*tid+1];
        __syncthreads();
        {
            const size_t rf = (size_t)(2048 + wrow);
            const float4* wi = (const float4*)(wWih + rf*512) + lane8*16;
            const float4* wh = (const float4*)(wWhh + rf*512) + lane8*16;
            const float4* hv = (const float4*)(hwh + 512) + lane8*16;
            const float* xp = sX + lane8*64;
            float acc = 0.f;
            #pragma unroll
            for (int j = 0; j < 16; ++j){
                float4 h4 = hv[j];
                acc += dot4(wi[j], xp + 4*j);
                float4 w4 = wh[j];
                acc += w4.x*h4.x + w4.y*h4.y + w4.z*h4.z + w4.w*h4.w;
            }
            #pragma unroll
            for (int m = 4; m >= 1; m >>= 1) acc += __shfl_xor(acc, m, 64);
            if (lane8 == 0) sgw[rg8] = acc + wbih[rf] + wbhh[rf];
        }
        __syncthreads();
        if (tid < 8){
            int u2 = (bx << 3) + tid;
            float gi = sigf(sgw[tid*4+0]);
            float gf = sigf(sgw[tid*4+1]);
            float gg = tanhf_(sgw[tid*4+2]);
            float go = sigf(sgw[tid*4+3]);
            float c = gf * hwc[512 + u2] + gi * gg;
            float h = go * tanhf_(c);
            ws[2560 + u2] = h;
            out[50000 + 512 + u2] = h;
            out[51024 + 512 + u2] = c;
        }
        gbar(bar, 15, NCHAR);
        if (bx == 0 && tid == 0)
            __hip_atomic_store(bar + FLAG_SLOT, 1, __ATOMIC_RELEASE, __HIP_MEMORY_SCOPE_AGENT);
    } else {
        // ---- prefetch dec_W into LLC, 8 loads in flight per thread ----
        const float4* dw = (const float4*)dec_W;
        const int gid = (bx - NCHAR)*256 + tid;     // 0..49151
        float acc = 0.f;
        // 6,400,000 float4 total; stride 49152; unroll 8 (393216/outer iter)
        for (int base = gid; base < 6400000; base += 393216){
            #pragma unroll
            for (int j = 0; j < 8; ++j){
                int idx = base + j*49152;
                if (idx < 6400000){
                    float4 v = dw[idx];
                    acc += v.x + v.y + v.z + v.w;
                }
            }
        }
        ws[8192 + gid] = acc;   // anti-DCE dump
        __syncthreads();
        if (tid == 0){
            while (__hip_atomic_load(bar + FLAG_SLOT, __ATOMIC_RELAXED, __HIP_MEMORY_SCOPE_AGENT) == 0)
                __builtin_amdgcn_s_sleep(4);
            (void)__hip_atomic_load(bar + FLAG_SLOT, __ATOMIC_ACQUIRE, __HIP_MEMORY_SCOPE_AGENT);
        }
        __syncthreads();
    }

    // ---- decoder: all 256 blocks, 4 rows per wave-iteration (8 loads in flight) ----
    const int lane = tid & 63;
    const int wid = (bx << 2) + (tid >> 6);   // 0..1023
    const float4* hp = (const float4*)(ws + 2560) + lane*2;
    float4 ha = hp[0], hb = hp[1];
    float hx0[4] = {ha.x, ha.y, ha.z, ha.w};
    float hx1[4] = {hb.x, hb.y, hb.z, hb.w};
    // 50000 % 4 == 0, so row groups of 4 need no tail guard.
    for (int r0 = wid*4; r0 < 50000; r0 += 4096){
        const float4* wp = (const float4*)(dec_W + (size_t)r0*512) + lane*2;
        float4 pa = wp[0],   pb = wp[1];      // row r0   (+0   float4s)
        float4 qa = wp[128], qb = wp[129];    // row r0+1 (+128)
        float4 ra = wp[256], rb = wp[257];    // row r0+2
        float4 sa = wp[384], sb = wp[385];    // row r0+3
        float a0 = dot4(pa, hx0) + dot4(pb, hx1);
        float a1 = dot4(qa, hx0) + dot4(qb, hx1);
        float a2 = dot4(ra, hx0) + dot4(rb, hx1);
        float a3 = dot4(sa, hx0) + dot4(sb, hx1);
        #pragma unroll
        for (int m = 32; m >= 1; m >>= 1){
            a0 += __shfl_xor(a0, m, 64);
            a1 += __shfl_xor(a1, m, 64);
            a2 += __shfl_xor(a2, m, 64);
            a3 += __shfl_xor(a3, m, 64);
        }
        if (lane == 0){
            out[r0]     = a0 + dec_b[r0];
            out[r0 + 1] = a1 + dec_b[r0 + 1];
            out[r0 + 2] = a2 + dec_b[r0 + 2];
            out[r0 + 3] = a3 + dec_b[r0 + 3];
        }
    }
}

extern "C" void kernel_launch(void* const* d_in, const int* in_sizes, int n_in,
                              void* d_out, int out_size, void* d_ws, size_t ws_size,
                              hipStream_t stream)
{
    const int*   x_word   = (const int*)d_in[0];
    const int*   x_char   = (const int*)d_in[1];
    const float* hwh      = (const float*)d_in[2];
    const float* hwc      = (const float*)d_in[3];
    const float* hch      = (const float*)d_in[4];
    const float* hcc      = (const float*)d_in[5];
    const float* word_emb = (const float*)d_in[6];
    const float* wWih     = (const float*)d_in[7];
    const float* wWhh     = (const float*)d_in[8];
    const float* wbih     = (const float*)d_in[9];
    const float* wbhh     = (const float*)d_in[10];
    const float* dec_W    = (const float*)d_in[11];
    const float* dec_b    = (const float*)d_in[12];
    const float* char_emb = (const float*)d_in[13];
    const float* cWih     = (const float*)d_in[14];
    const float* cWhh     = (const float*)d_in[15];
    const float* cbih     = (const float*)d_in[16];
    const float* cbhh     = (const float*)d_in[17];
    const float* cte      = (const float*)d_in[18];
    const float* g_w      = (const float*)d_in[19];
    const float* g_b      = (const float*)d_in[20];

    float* ws = (float*)d_ws;
    int* bar = (int*)((char*)d_ws + BAR_I*4);
    hipMemsetAsync(bar, 0, 32 * sizeof(int), stream);

    hipLaunchKernelGGL(k_fused, dim3(NBLK), dim3(256), 0, stream,
        x_word, x_char, hwh, hwc, hch, hcc, word_emb, wWih, wWhh, wbih, wbhh,
        dec_W, dec_b, char_emb, cWih, cWhh, cbih, cbhh, cte, g_w, g_b,
        ws, bar, (float*)d_out);
}